// Round 1
// baseline (398.017 us; speedup 1.0000x reference)
//
#include <hip/hip_runtime.h>
#include <cstdint>
#include <cstddef>

typedef __bf16 bf16;
typedef __bf16 bf16x8 __attribute__((ext_vector_type(8)));
typedef float f32x4 __attribute__((ext_vector_type(4)));

static constexpr int Cdim = 512;
static constexpr int Ndim = 4096;   // 64*64
static constexpr size_t NCe = (size_t)Ndim * Cdim;  // 2097152

#define AS1 __attribute__((address_space(1)))
#define AS3 __attribute__((address_space(3)))

__device__ __forceinline__ void async16(bf16* lds, const bf16* g) {
  __builtin_amdgcn_global_load_lds((AS1 void*)(g), (AS3 void*)(lds), 16, 0, 0);
}

// ---------------- weight fp32 -> bf16 convert (4 x 512x512) ----------------
__global__ __launch_bounds__(256) void cvt4(const float* __restrict__ s0, const float* __restrict__ s1,
                                            const float* __restrict__ s2, const float* __restrict__ s3,
                                            bf16* __restrict__ d0, bf16* __restrict__ d1,
                                            bf16* __restrict__ d2, bf16* __restrict__ d3) {
  int i = blockIdx.x * 256 + threadIdx.x;   // 0 .. 4*262144-1
  int sel = i >> 18;
  int j = i & 262143;
  const float* s = sel == 0 ? s0 : sel == 1 ? s1 : sel == 2 ? s2 : s3;
  bf16* d = sel == 0 ? d0 : sel == 1 ? d1 : sel == 2 ? d2 : d3;
  d[j] = (bf16)s[j];
}

// ---------------- groupnorm stats: one block per (b,g), 16ch x 4096 ----------------
__global__ __launch_bounds__(256) void gn_stats(const float* __restrict__ x, float* __restrict__ stats) {
  const int bg = blockIdx.x;  // b*32+g ; offset = bg*65536 floats
  const float4* base = (const float4*)(x + (size_t)bg * 65536);
  float s = 0.f, q = 0.f;
  for (int i = threadIdx.x; i < 16384; i += 256) {
    float4 v = base[i];
    s += v.x + v.y + v.z + v.w;
    q += v.x * v.x + v.y * v.y + v.z * v.z + v.w * v.w;
  }
#pragma unroll
  for (int off = 32; off > 0; off >>= 1) { s += __shfl_xor(s, off); q += __shfl_xor(q, off); }
  __shared__ float rs[4], rq[4];
  const int lane = threadIdx.x & 63, wave = threadIdx.x >> 6;
  if (lane == 0) { rs[wave] = s; rq[wave] = q; }
  __syncthreads();
  if (threadIdx.x == 0) {
    float st = rs[0] + rs[1] + rs[2] + rs[3];
    float qt = rq[0] + rq[1] + rq[2] + rq[3];
    float mean = st * (1.f / 65536.f);
    float var = qt * (1.f / 65536.f) - mean * mean;
    stats[2 * bg] = mean;
    stats[2 * bg + 1] = rsqrtf(var + 1e-6f);
  }
}

// ---------------- normalize + transpose: x[b,c,n] -> hn_t[b,n,c] bf16 ----------------
__global__ __launch_bounds__(256) void gn_norm_t(const float* __restrict__ x, const float* __restrict__ stats,
                                                 const float* __restrict__ gamma, const float* __restrict__ beta,
                                                 bf16* __restrict__ hn_t) {
  const int n0 = blockIdx.x * 64, c0 = blockIdx.y * 64, b = blockIdx.z;
  const float* xb = x + (size_t)b * NCe;
  __shared__ float tile[64][65];
  const int t = threadIdx.x;
  const int tx = t & 15, ty = t >> 4;
#pragma unroll
  for (int i = 0; i < 4; ++i) {
    int c = ty * 4 + i;
    float4 v = *(const float4*)&xb[(size_t)(c0 + c) * Ndim + n0 + tx * 4];
    tile[c][tx * 4 + 0] = v.x; tile[c][tx * 4 + 1] = v.y;
    tile[c][tx * 4 + 2] = v.z; tile[c][tx * 4 + 3] = v.w;
  }
  __syncthreads();
  const int c8 = t & 7, nr = t >> 3;  // c8: 8-wide c chunk, nr: 0..31
#pragma unroll
  for (int i = 0; i < 2; ++i) {
    int nl = nr + i * 32;
    bf16x8 o;
#pragma unroll
    for (int j = 0; j < 8; ++j) {
      int cl = c8 * 8 + j;
      int c = c0 + cl;
      int g = b * 32 + (c >> 4);
      float mean = stats[2 * g], rstd = stats[2 * g + 1];
      float v = (tile[cl][nl] - mean) * rstd * gamma[c] + beta[c];
      o[j] = (bf16)v;
    }
    *(bf16x8*)&hn_t[((size_t)b * Ndim + n0 + nl) * Cdim + c0 + c8 * 8] = o;
  }
}

// ---------------- bt-GEMM: C[m,n] = sum_k A[m,k]*B[n,k]; ldA=ldB=K, ldC=N ----------------
// EPI: 0 bf16 + bias[col], 1 bf16 + bias[row], 2 bf16 * scale, 3 bf16 plain,
//      4 f32 + bias[row] + resid[row*N+col]
template <int BMT, int BNT, int EPI>
__global__ __launch_bounds__(256) void gemm_bt(const bf16* __restrict__ A, size_t asb,
                                               const bf16* __restrict__ B, size_t bsb,
                                               void* __restrict__ Cp, size_t csb,
                                               int M, int N, int K,
                                               const float* __restrict__ bias, float scale,
                                               const float* __restrict__ resid, size_t rsb) {
  constexpr int MI = BMT / 32, NI = BNT / 32;
  const size_t zb = blockIdx.z;
  A += zb * asb;
  B += zb * bsb;
  if constexpr (EPI == 4) resid += zb * rsb;
  const size_t cofs = zb * csb;
  const int m0 = blockIdx.y * BMT, n0 = blockIdx.x * BNT;
  __shared__ bf16 As[BMT * 32];
  __shared__ bf16 Bs[BNT * 32];
  const int tid = threadIdx.x;
  const int lane = tid & 63, wave = tid >> 6;
  // staging: chunk idx = it*256+tid; row = idx>>2, 16B chunk = idx&3; LDS elem off = idx*8
  const bf16* gA = A + (size_t)(m0 + (tid >> 2)) * K + (tid & 3) * 8;
  const bf16* gB = B + (size_t)(n0 + (tid >> 2)) * K + (tid & 3) * 8;
  bf16* lA = As + tid * 8;
  bf16* lB = Bs + tid * 8;
  const int wm = (wave & 1) * (BMT / 2), wn = (wave >> 1) * (BNT / 2);
  const int lrow = lane & 15, koff = (lane >> 4) * 8;
  const bf16* fA = As + (wm + lrow) * 32 + koff;
  const bf16* fB = Bs + (wn + lrow) * 32 + koff;
  f32x4 acc[MI][NI];
#pragma unroll
  for (int mi = 0; mi < MI; ++mi)
#pragma unroll
    for (int ni = 0; ni < NI; ++ni) acc[mi][ni] = (f32x4){0.f, 0.f, 0.f, 0.f};

  for (int k0 = 0; k0 < K; k0 += 32) {
    __syncthreads();
#pragma unroll
    for (int it = 0; it < BMT / 64; ++it) async16(lA + it * 2048, gA + (size_t)it * 64 * K + k0);
#pragma unroll
    for (int it = 0; it < BNT / 64; ++it) async16(lB + it * 2048, gB + (size_t)it * 64 * K + k0);
    __syncthreads();
    bf16x8 af[MI], bfr[NI];
#pragma unroll
    for (int mi = 0; mi < MI; ++mi) af[mi] = *(const bf16x8*)(fA + mi * 512);
#pragma unroll
    for (int ni = 0; ni < NI; ++ni) bfr[ni] = *(const bf16x8*)(fB + ni * 512);
#pragma unroll
    for (int mi = 0; mi < MI; ++mi)
#pragma unroll
      for (int ni = 0; ni < NI; ++ni)
        acc[mi][ni] = __builtin_amdgcn_mfma_f32_16x16x32_bf16(af[mi], bfr[ni], acc[mi][ni], 0, 0, 0);
  }

  const int col = lane & 15, rb = (lane >> 4) * 4;
#pragma unroll
  for (int mi = 0; mi < MI; ++mi) {
#pragma unroll
    for (int ni = 0; ni < NI; ++ni) {
      const int gn = n0 + wn + ni * 16 + col;
      const int gm0 = m0 + wm + mi * 16 + rb;
#pragma unroll
      for (int r = 0; r < 4; ++r) {
        const int gm = gm0 + r;
        const size_t ci = cofs + (size_t)gm * N + gn;
        float vv = acc[mi][ni][r];
        if constexpr (EPI == 0) ((bf16*)Cp)[ci] = (bf16)(vv + bias[gn]);
        else if constexpr (EPI == 1) ((bf16*)Cp)[ci] = (bf16)(vv + bias[gm]);
        else if constexpr (EPI == 2) ((bf16*)Cp)[ci] = (bf16)(vv * scale);
        else if constexpr (EPI == 3) ((bf16*)Cp)[ci] = (bf16)vv;
        else ((float*)Cp)[ci] = vv + bias[gm] + resid[(size_t)gm * N + gn];
      }
    }
  }
}

// ---------------- in-place row softmax over S [4096 x 4096] bf16 ----------------
__global__ __launch_bounds__(256) void softmax_rows(bf16* __restrict__ S) {
  const int t = threadIdx.x;
  bf16* p = S + (size_t)blockIdx.x * 4096 + t * 16;
  bf16x8 a = *(const bf16x8*)p;
  bf16x8 c = *(const bf16x8*)(p + 8);
  float f[16];
#pragma unroll
  for (int j = 0; j < 8; ++j) { f[j] = (float)a[j]; f[8 + j] = (float)c[j]; }
  float m = f[0];
#pragma unroll
  for (int j = 1; j < 16; ++j) m = fmaxf(m, f[j]);
#pragma unroll
  for (int off = 32; off > 0; off >>= 1) m = fmaxf(m, __shfl_xor(m, off));
  __shared__ float wm_[4], ws_[4];
  const int lane = t & 63, wave = t >> 6;
  if (lane == 0) wm_[wave] = m;
  __syncthreads();
  m = fmaxf(fmaxf(wm_[0], wm_[1]), fmaxf(wm_[2], wm_[3]));
  float s = 0.f;
#pragma unroll
  for (int j = 0; j < 16; ++j) { f[j] = __expf(f[j] - m); s += f[j]; }
#pragma unroll
  for (int off = 32; off > 0; off >>= 1) s += __shfl_xor(s, off);
  if (lane == 0) ws_[wave] = s;
  __syncthreads();
  s = ws_[0] + ws_[1] + ws_[2] + ws_[3];
  const float r = 1.f / s;
#pragma unroll
  for (int j = 0; j < 8; ++j) { a[j] = (bf16)(f[j] * r); c[j] = (bf16)(f[8 + j] * r); }
  *(bf16x8*)p = a;
  *(bf16x8*)(p + 8) = c;
}

extern "C" void kernel_launch(void* const* d_in, const int* in_sizes, int n_in,
                              void* d_out, int out_size, void* d_ws, size_t ws_size,
                              hipStream_t stream) {
  (void)in_sizes; (void)n_in; (void)out_size; (void)ws_size;
  const float* x     = (const float*)d_in[0];
  const float* gamma = (const float*)d_in[1];
  const float* beta  = (const float*)d_in[2];
  const float* wq = (const float*)d_in[3];
  const float* bq = (const float*)d_in[4];
  const float* wk = (const float*)d_in[5];
  const float* bk = (const float*)d_in[6];
  const float* wv = (const float*)d_in[7];
  const float* bv = (const float*)d_in[8];
  const float* wo = (const float*)d_in[9];
  const float* bo = (const float*)d_in[10];
  float* out = (float*)d_out;

  char* ws = (char*)d_ws;
  size_t off = 0;
  auto alloc = [&](size_t bytes) {
    void* p = ws + off;
    off += (bytes + 1023) & ~(size_t)1023;
    return p;
  };
  bf16* wqb = (bf16*)alloc(262144 * 2);
  bf16* wkb = (bf16*)alloc(262144 * 2);
  bf16* wvb = (bf16*)alloc(262144 * 2);
  bf16* wob = (bf16*)alloc(262144 * 2);
  float* stats = (float*)alloc(64 * 2 * sizeof(float));
  bf16* hn_t = (bf16*)alloc(NCe * 2 * 2);   // [b][n][c]
  bf16* q_t  = (bf16*)alloc(NCe * 2 * 2);   // [b][n][c]
  bf16* k_t  = (bf16*)alloc(NCe * 2 * 2);   // [b][n][c]
  bf16* v_   = (bf16*)alloc(NCe * 2 * 2);   // [b][c][n]
  bf16* o_t  = (bf16*)alloc(NCe * 2 * 2);   // [b][n][c]
  bf16* S    = (bf16*)alloc((size_t)Ndim * Ndim * 2);  // one batch, reused

  cvt4<<<4096, 256, 0, stream>>>(wq, wk, wv, wo, wqb, wkb, wvb, wob);
  gn_stats<<<64, 256, 0, stream>>>(x, stats);
  gn_norm_t<<<dim3(64, 8, 2), 256, 0, stream>>>(x, stats, gamma, beta, hn_t);

  const float scale = 0.044194173824159216f;  // 512^-0.5

  // q_t[n,o] = hn_t . wq^T + bq   (M=4096, N=512, K=512), batched over z
  gemm_bt<128, 128, 0><<<dim3(4, 32, 2), 256, 0, stream>>>(hn_t, NCe, wqb, 0, q_t, NCe,
                                                           Ndim, Cdim, Cdim, bq, 1.f, nullptr, 0);
  gemm_bt<128, 128, 0><<<dim3(4, 32, 2), 256, 0, stream>>>(hn_t, NCe, wkb, 0, k_t, NCe,
                                                           Ndim, Cdim, Cdim, bk, 1.f, nullptr, 0);
  // v[c,n] = wv . hn_t^T + bv    (M=512, N=4096, K=512)
  gemm_bt<128, 128, 1><<<dim3(32, 4, 2), 256, 0, stream>>>(wvb, 0, hn_t, NCe, v_, NCe,
                                                           Cdim, Ndim, Cdim, bv, 1.f, nullptr, 0);

  for (int b = 0; b < 2; ++b) {
    // S[i,j] = scale * q_t . k_t^T   (M=N=4096, K=512)
    gemm_bt<128, 128, 2><<<dim3(32, 32, 1), 256, 0, stream>>>(q_t + (size_t)b * NCe, 0,
                                                              k_t + (size_t)b * NCe, 0, S, 0,
                                                              Ndim, Ndim, Cdim, nullptr, scale, nullptr, 0);
    softmax_rows<<<4096, 256, 0, stream>>>(S);
    // o_t[i,c] = P . v^T   (M=4096, N=512, K=4096); 64x128 tile -> 256 blocks
    gemm_bt<64, 128, 3><<<dim3(4, 64, 1), 256, 0, stream>>>(S, 0, v_ + (size_t)b * NCe, 0,
                                                            o_t + (size_t)b * NCe, 0,
                                                            Ndim, Cdim, Ndim, nullptr, 1.f, nullptr, 0);
  }
  // out[o,n] = wo . o_t^T + bo + x   (M=512, N=4096, K=512), fp32 out, batched
  gemm_bt<128, 128, 4><<<dim3(32, 4, 2), 256, 0, stream>>>(wob, 0, o_t, NCe, out, NCe,
                                                           Cdim, Ndim, Cdim, bo, 1.f, x, NCe);
}

// Round 2
// 313.953 us; speedup vs baseline: 1.2678x; 1.2678x over previous
//
#include <hip/hip_runtime.h>
#include <cstdint>
#include <cstddef>

typedef __bf16 bf16;
typedef __bf16 bf16x8 __attribute__((ext_vector_type(8)));
typedef float f32x4 __attribute__((ext_vector_type(4)));

static constexpr int Cdim = 512;
static constexpr int Ndim = 4096;   // 64*64
static constexpr size_t NCe = (size_t)Ndim * Cdim;          // 2097152
static constexpr size_t QKVs = (size_t)Ndim * 1536;         // per-batch qkv_t stride (elems)
static constexpr size_t Ss = (size_t)Ndim * Ndim;           // per-batch S stride (elems)

#define AS1 __attribute__((address_space(1)))
#define AS3 __attribute__((address_space(3)))

__device__ __forceinline__ void async16(bf16* lds, const bf16* g) {
  __builtin_amdgcn_global_load_lds((AS1 void*)(g), (AS3 void*)(lds), 16, 0, 0);
}

// ---------------- prep: weights fp32->bf16 (concat wq|wk|wv rows), wo, concat bias ----------------
__global__ __launch_bounds__(256) void prep(const float* __restrict__ wq, const float* __restrict__ wk,
                                            const float* __restrict__ wv, const float* __restrict__ wo,
                                            const float* __restrict__ bq, const float* __restrict__ bk,
                                            const float* __restrict__ bv,
                                            bf16* __restrict__ wqkv, bf16* __restrict__ wob,
                                            float* __restrict__ bqkv) {
  int i = blockIdx.x * 256 + threadIdx.x;
  if (i < 262144) wqkv[i] = (bf16)wq[i];
  else if (i < 524288) wqkv[i] = (bf16)wk[i - 262144];
  else if (i < 786432) wqkv[i] = (bf16)wv[i - 524288];
  else if (i < 1048576) wob[i - 786432] = (bf16)wo[i - 786432];
  else if (i < 1048576 + 1536) {
    int j = i - 1048576;
    bqkv[j] = j < 512 ? bq[j] : j < 1024 ? bk[j - 512] : bv[j - 1024];
  }
}

// ---------------- groupnorm stats: one block per (b,g), 16ch x 4096 ----------------
__global__ __launch_bounds__(256) void gn_stats(const float* __restrict__ x, float* __restrict__ stats) {
  const int bg = blockIdx.x;
  const float4* base = (const float4*)(x + (size_t)bg * 65536);
  float s = 0.f, q = 0.f;
  for (int i = threadIdx.x; i < 16384; i += 256) {
    float4 v = base[i];
    s += v.x + v.y + v.z + v.w;
    q += v.x * v.x + v.y * v.y + v.z * v.z + v.w * v.w;
  }
#pragma unroll
  for (int off = 32; off > 0; off >>= 1) { s += __shfl_xor(s, off); q += __shfl_xor(q, off); }
  __shared__ float rs[4], rq[4];
  const int lane = threadIdx.x & 63, wave = threadIdx.x >> 6;
  if (lane == 0) { rs[wave] = s; rq[wave] = q; }
  __syncthreads();
  if (threadIdx.x == 0) {
    float st = rs[0] + rs[1] + rs[2] + rs[3];
    float qt = rq[0] + rq[1] + rq[2] + rq[3];
    float mean = st * (1.f / 65536.f);
    float var = qt * (1.f / 65536.f) - mean * mean;
    stats[2 * bg] = mean;
    stats[2 * bg + 1] = rsqrtf(var + 1e-6f);
  }
}

// ---------------- normalize + transpose: x[b,c,n] -> hn_t[b,n,c] bf16 ----------------
__global__ __launch_bounds__(256) void gn_norm_t(const float* __restrict__ x, const float* __restrict__ stats,
                                                 const float* __restrict__ gamma, const float* __restrict__ beta,
                                                 bf16* __restrict__ hn_t) {
  const int n0 = blockIdx.x * 64, c0 = blockIdx.y * 64, b = blockIdx.z;
  const float* xb = x + (size_t)b * NCe;
  __shared__ float tile[64][65];
  const int t = threadIdx.x;
  const int tx = t & 15, ty = t >> 4;
#pragma unroll
  for (int i = 0; i < 4; ++i) {
    int c = ty * 4 + i;
    float4 v = *(const float4*)&xb[(size_t)(c0 + c) * Ndim + n0 + tx * 4];
    tile[c][tx * 4 + 0] = v.x; tile[c][tx * 4 + 1] = v.y;
    tile[c][tx * 4 + 2] = v.z; tile[c][tx * 4 + 3] = v.w;
  }
  __syncthreads();
  const int c8 = t & 7, nr = t >> 3;
#pragma unroll
  for (int i = 0; i < 2; ++i) {
    int nl = nr + i * 32;
    bf16x8 o;
#pragma unroll
    for (int j = 0; j < 8; ++j) {
      int cl = c8 * 8 + j;
      int c = c0 + cl;
      int g = b * 32 + (c >> 4);
      float mean = stats[2 * g], rstd = stats[2 * g + 1];
      float v = (tile[cl][nl] - mean) * rstd * gamma[c] + beta[c];
      o[j] = (bf16)v;
    }
    *(bf16x8*)&hn_t[((size_t)b * Ndim + n0 + nl) * Cdim + c0 + c8 * 8] = o;
  }
}

// ---------------- bt-GEMM: C[m,n] = sum_k A[m,k]*B[n,k]; ldc = N ----------------
// EPI: 0 bf16 + bias[col], 2 bf16 * scale, 3 bf16 plain,
//      4 fp32 atomicAdd (+ bias[row] + resid[row*N+col] on split 0)
template <int BMT, int BNT, int EPI, int SPLITK>
__global__ __launch_bounds__(256) void gemm_bt(const bf16* __restrict__ A, size_t lda, size_t asb,
                                               const bf16* __restrict__ B, size_t ldb, size_t bsb,
                                               void* __restrict__ Cp, size_t csb,
                                               int M, int N, int K,
                                               const float* __restrict__ bias, float scale,
                                               const float* __restrict__ resid, size_t rsb) {
  constexpr int MI = BMT / 32, NI = BNT / 32;
  const int zb = blockIdx.z / SPLITK, sk = blockIdx.z % SPLITK;
  A += (size_t)zb * asb;
  B += (size_t)zb * bsb;
  if constexpr (EPI == 4) resid += (size_t)zb * rsb;
  const size_t cofs = (size_t)zb * csb;
  const int kspan = K / SPLITK;
  const int kbeg = sk * kspan, kend = kbeg + kspan;
  const int m0 = blockIdx.y * BMT, n0 = blockIdx.x * BNT;
  __shared__ bf16 As[BMT * 32];
  __shared__ bf16 Bs[BNT * 32];
  const int tid = threadIdx.x;
  const int lane = tid & 63, wave = tid >> 6;
  const bf16* gA = A + (size_t)(m0 + (tid >> 2)) * lda + (tid & 3) * 8;
  const bf16* gB = B + (size_t)(n0 + (tid >> 2)) * ldb + (tid & 3) * 8;
  bf16* lA = As + tid * 8;
  bf16* lB = Bs + tid * 8;
  const int wm = (wave & 1) * (BMT / 2), wn = (wave >> 1) * (BNT / 2);
  const int lrow = lane & 15, koff = (lane >> 4) * 8;
  const bf16* fA = As + (wm + lrow) * 32 + koff;
  const bf16* fB = Bs + (wn + lrow) * 32 + koff;
  f32x4 acc[MI][NI];
#pragma unroll
  for (int mi = 0; mi < MI; ++mi)
#pragma unroll
    for (int ni = 0; ni < NI; ++ni) acc[mi][ni] = (f32x4){0.f, 0.f, 0.f, 0.f};

  for (int k0 = kbeg; k0 < kend; k0 += 32) {
    __syncthreads();
#pragma unroll
    for (int it = 0; it < BMT / 64; ++it) async16(lA + it * 2048, gA + (size_t)it * 64 * lda + k0);
#pragma unroll
    for (int it = 0; it < BNT / 64; ++it) async16(lB + it * 2048, gB + (size_t)it * 64 * ldb + k0);
    __syncthreads();
    bf16x8 af[MI], bfr[NI];
#pragma unroll
    for (int mi = 0; mi < MI; ++mi) af[mi] = *(const bf16x8*)(fA + mi * 512);
#pragma unroll
    for (int ni = 0; ni < NI; ++ni) bfr[ni] = *(const bf16x8*)(fB + ni * 512);
#pragma unroll
    for (int mi = 0; mi < MI; ++mi)
#pragma unroll
      for (int ni = 0; ni < NI; ++ni)
        acc[mi][ni] = __builtin_amdgcn_mfma_f32_16x16x32_bf16(af[mi], bfr[ni], acc[mi][ni], 0, 0, 0);
  }

  const int col = lane & 15, rb = (lane >> 4) * 4;
#pragma unroll
  for (int mi = 0; mi < MI; ++mi) {
#pragma unroll
    for (int ni = 0; ni < NI; ++ni) {
      const int gn = n0 + wn + ni * 16 + col;
      const int gm0 = m0 + wm + mi * 16 + rb;
#pragma unroll
      for (int r = 0; r < 4; ++r) {
        const int gm = gm0 + r;
        const size_t ci = cofs + (size_t)gm * N + gn;
        float vv = acc[mi][ni][r];
        if constexpr (EPI == 0) ((bf16*)Cp)[ci] = (bf16)(vv + bias[gn]);
        else if constexpr (EPI == 2) ((bf16*)Cp)[ci] = (bf16)(vv * scale);
        else if constexpr (EPI == 3) ((bf16*)Cp)[ci] = (bf16)vv;
        else if constexpr (EPI == 4) {
          if (SPLITK == 1 || sk == 0) vv += bias[gm] + resid[(size_t)gm * N + gn];
          atomicAdd(&((float*)Cp)[ci], vv);
        }
      }
    }
  }
}

// ---------------- in-place row softmax over S [z][4096][4096] bf16 ----------------
__global__ __launch_bounds__(256) void softmax_rows(bf16* __restrict__ S, size_t bstride) {
  const int t = threadIdx.x;
  bf16* p = S + (size_t)blockIdx.y * bstride + (size_t)blockIdx.x * 4096 + t * 16;
  bf16x8 a = *(const bf16x8*)p;
  bf16x8 c = *(const bf16x8*)(p + 8);
  float f[16];
#pragma unroll
  for (int j = 0; j < 8; ++j) { f[j] = (float)a[j]; f[8 + j] = (float)c[j]; }
  float m = f[0];
#pragma unroll
  for (int j = 1; j < 16; ++j) m = fmaxf(m, f[j]);
#pragma unroll
  for (int off = 32; off > 0; off >>= 1) m = fmaxf(m, __shfl_xor(m, off));
  __shared__ float wm_[4], ws_[4];
  const int lane = t & 63, wave = t >> 6;
  if (lane == 0) wm_[wave] = m;
  __syncthreads();
  m = fmaxf(fmaxf(wm_[0], wm_[1]), fmaxf(wm_[2], wm_[3]));
  float s = 0.f;
#pragma unroll
  for (int j = 0; j < 16; ++j) { f[j] = __expf(f[j] - m); s += f[j]; }
#pragma unroll
  for (int off = 32; off > 0; off >>= 1) s += __shfl_xor(s, off);
  if (lane == 0) ws_[wave] = s;
  __syncthreads();
  s = ws_[0] + ws_[1] + ws_[2] + ws_[3];
  const float r = 1.f / s;
#pragma unroll
  for (int j = 0; j < 8; ++j) { a[j] = (bf16)(f[j] * r); c[j] = (bf16)(f[8 + j] * r); }
  *(bf16x8*)p = a;
  *(bf16x8*)(p + 8) = c;
}

extern "C" void kernel_launch(void* const* d_in, const int* in_sizes, int n_in,
                              void* d_out, int out_size, void* d_ws, size_t ws_size,
                              hipStream_t stream) {
  (void)in_sizes; (void)n_in; (void)out_size;
  const float* x     = (const float*)d_in[0];
  const float* gamma = (const float*)d_in[1];
  const float* beta  = (const float*)d_in[2];
  const float* wq = (const float*)d_in[3];
  const float* bq = (const float*)d_in[4];
  const float* wk = (const float*)d_in[5];
  const float* bk = (const float*)d_in[6];
  const float* wv = (const float*)d_in[7];
  const float* bv = (const float*)d_in[8];
  const float* wo = (const float*)d_in[9];
  const float* bo = (const float*)d_in[10];
  float* out = (float*)d_out;

  char* ws = (char*)d_ws;
  size_t off = 0;
  auto alloc = [&](size_t bytes) {
    void* p = ws + off;
    off += (bytes + 1023) & ~(size_t)1023;
    return p;
  };
  bf16* wqkv  = (bf16*)alloc(786432 * 2);         // [1536][512]
  bf16* wob   = (bf16*)alloc(262144 * 2);         // [512][512]
  float* bqkv = (float*)alloc(1536 * 4);
  float* stats = (float*)alloc(64 * 2 * 4);
  bf16* hn_t  = (bf16*)alloc(NCe * 2 * 2);        // [b][n][512]
  bf16* qkv_t = (bf16*)alloc(QKVs * 2 * 2);       // [b][n][1536] : q|k|v
  bf16* vo    = (bf16*)alloc(NCe * 2 * 2);        // [b][512][4096] = wo . v
  // S last: 2-batch if workspace allows, else 1-batch reused
  const bool two = (off + 2 * Ss * 2) <= ws_size;
  bf16* S = (bf16*)alloc((two ? 2 * Ss : Ss) * 2);

  hipMemsetAsync(out, 0, 2 * NCe * sizeof(float), stream);
  prep<<<4102, 256, 0, stream>>>(wq, wk, wv, wo, bq, bk, bv, wqkv, wob, bqkv);
  gn_stats<<<64, 256, 0, stream>>>(x, stats);
  gn_norm_t<<<dim3(64, 8, 2), 256, 0, stream>>>(x, stats, gamma, beta, hn_t);

  const float scale = 0.044194173824159216f;  // 512^-0.5

  // qkv_t[b][n][o] = hn_t . wqkv^T + bqkv   (M=4096, N=1536, K=512)
  gemm_bt<128, 128, 0, 1><<<dim3(12, 32, 2), 256, 0, stream>>>(
      hn_t, 512, NCe, wqkv, 512, 0, qkv_t, QKVs, Ndim, 1536, Cdim, bqkv, 1.f, nullptr, 0);
  // vo[b][o][j] = wo . v + (bv folded via v's bias)   (M=512, N=4096, K=512)
  gemm_bt<64, 128, 3, 1><<<dim3(32, 8, 2), 256, 0, stream>>>(
      wob, 512, 0, qkv_t + 1024, 1536, QKVs, vo, NCe, Cdim, Ndim, Cdim, nullptr, 1.f, nullptr, 0);

  if (two) {
    // S[b][i][j] = scale * q . k   (M=N=4096, K=512)
    gemm_bt<128, 128, 2, 1><<<dim3(32, 32, 2), 256, 0, stream>>>(
        qkv_t, 1536, QKVs, qkv_t + 512, 1536, QKVs, S, Ss, Ndim, Ndim, Cdim, nullptr, scale, nullptr, 0);
    softmax_rows<<<dim3(4096, 2), 256, 0, stream>>>(S, Ss);
    // out[b][o][i] += sum_j vo[o,j] P[i,j]  (+ bo + x on split 0); M=512,N=4096,K=4096, split-K=2
    gemm_bt<64, 128, 4, 2><<<dim3(32, 8, 4), 256, 0, stream>>>(
        vo, 4096, NCe, S, 4096, Ss, out, NCe, Cdim, Ndim, Ndim, bo, 1.f, x, NCe);
  } else {
    for (int b = 0; b < 2; ++b) {
      gemm_bt<128, 128, 2, 1><<<dim3(32, 32, 1), 256, 0, stream>>>(
          qkv_t + b * QKVs, 1536, 0, qkv_t + b * QKVs + 512, 1536, 0, S, 0,
          Ndim, Ndim, Cdim, nullptr, scale, nullptr, 0);
      softmax_rows<<<dim3(4096, 1), 256, 0, stream>>>(S, 0);
      gemm_bt<64, 128, 4, 2><<<dim3(32, 8, 2), 256, 0, stream>>>(
          vo + b * NCe, 4096, 0, S, 4096, 0, out + b * NCe, 0,
          Cdim, Ndim, Ndim, bo, 1.f, x + b * NCe, 0);
    }
  }
}